// Round 6
// baseline (7218.820 us; speedup 1.0000x reference)
//
#include <hip/hip_runtime.h>
#include <hip/hip_bf16.h>

typedef short s16x8 __attribute__((ext_vector_type(8)));
typedef unsigned short u16;

#define NH 12
#define DH 64
#define DM 768
#define S_LEN 2048
#define B_SZ 4

static __device__ __forceinline__ u16 f2bf(float f) {
  __hip_bfloat16 h = __float2bfloat16(f);
  return __builtin_bit_cast(u16, h);
}
static __device__ __forceinline__ float bf2f(u16 x) {
  unsigned u = ((unsigned)x) << 16;
  return __builtin_bit_cast(float, u);
}

// ---------------------------------------------------------------------------
// Scalar NT GEMM (ground truth, no MFMA): C[m,n] = sum_k A[m,k]*W[n,k].
// A = x (8192 x 768 f32), W = wq/wk/wv (768 x 768 f32). Classic 16x16 LDS
// tile, one output/thread. Raw (un-roped) q/k/v written bf16 to (b,h,s,d);
// q pre-scaled by 1/sqrt(64) (linear, commutes with RoPE).
// ---------------------------------------------------------------------------
__global__ __launch_bounds__(256) void qkv_gemm_scalar(
    const float* __restrict__ x, const float* __restrict__ wq,
    const float* __restrict__ wk, const float* __restrict__ wv,
    u16* __restrict__ qo, u16* __restrict__ ko, u16* __restrict__ vo)
{
  const int z = blockIdx.z;                   // 0=q 1=k 2=v
  const float* W = (z == 0) ? wq : (z == 1) ? wk : wv;
  u16* O = (z == 0) ? qo : (z == 1) ? ko : vo;
  const int tx = threadIdx.x & 15, ty = threadIdx.x >> 4;
  const int m = blockIdx.x * 16 + ty;         // token 0..8191
  const int n = blockIdx.y * 16 + tx;         // out feature 0..767

  __shared__ float As[16][17];
  __shared__ float Ws[16][17];

  float acc = 0.f;
  for (int kt = 0; kt < DM; kt += 16) {
    As[ty][tx] = x[(size_t)m * DM + kt + tx];
    Ws[ty][tx] = W[(size_t)(blockIdx.y * 16 + ty) * DM + kt + tx];
    __syncthreads();
#pragma unroll
    for (int j = 0; j < 16; ++j) acc += As[ty][j] * Ws[tx][j];
    __syncthreads();
  }
  if (z == 0) acc *= 0.125f;

  const int b = m >> 11, s = m & (S_LEN - 1);
  const int h = n >> 6, d = n & 63;
  O[(((size_t)(b * NH + h)) * S_LEN + s) * DH + d] = f2bf(acc);
}

// ---------------------------------------------------------------------------
// Scalar RoPE, in place on q and k (bf16, (b,h,s,d)). One thread per
// (even,odd) pair — no cross-thread exchange. Precise sincosf (angles reach
// 2047 rad; native v_sin invalid past ~±256 revolutions).
// ---------------------------------------------------------------------------
#define NPAIRS (B_SZ * NH * S_LEN * 32)   // 3145728 per tensor

__global__ __launch_bounds__(256) void rope_scalar(u16* __restrict__ q,
                                                   u16* __restrict__ k)
{
  const int idx = blockIdx.x * 256 + threadIdx.x;   // 0 .. 2*NPAIRS-1 exact
  u16* buf = (idx < NPAIRS) ? q : k;
  const int id = (idx < NPAIRS) ? idx : idx - NPAIRS;
  const int i = id & 31;                    // freq index
  const int s = (id >> 5) & (S_LEN - 1);    // position
  const size_t off = ((size_t)(id >> 5)) * DH + 2 * i;  // (bh*2048+s)*64 + 2i
  const float e = bf2f(buf[off]), o = bf2f(buf[off + 1]);
  const float inv_freq = exp2f((float)(2 * i) * (-13.287712379549449f / 64.0f));
  float sv, cv;
  sincosf((float)s * inv_freq, &sv, &cv);
  buf[off]     = f2bf(e * cv - o * sv);
  buf[off + 1] = f2bf(e * sv + o * cv);
}

// ---------------------------------------------------------------------------
// Scalar flash attention. Block = 256 thr = 16 q-rows x 16 col-groups of one
// (b,h); 64-key tiles in LDS; online softmax by 16 owner threads; finite
// sentinel -1e30. Output -> d_out as FLOAT32, (b,s,dm) row-major.
// ---------------------------------------------------------------------------
#define TQ 16
#define TK 64
#define KPAD 72
#define SST 68

__global__ __launch_bounds__(256) void attn_scalar_kernel(
    const u16* __restrict__ q, const u16* __restrict__ k,
    const u16* __restrict__ v, float* __restrict__ o)
{
  const int qt = blockIdx.x;            // 16-query tile index (0..127)
  const int bh = blockIdx.y;            // 0..47
  const size_t base = (size_t)bh * S_LEN * DH;
  const int tid = threadIdx.x;

  __shared__ u16 Ql[TQ * KPAD];
  __shared__ u16 Kl[TK * KPAD];
  __shared__ u16 Vl[TK * KPAD];
  __shared__ float Sl[TQ * SST];
  __shared__ float al[TQ];
  __shared__ float ll[TQ];

  const int q0 = qt * TQ;

  if (tid < 128) {                      // stage Q tile (16 x 64)
    const int r = tid >> 3, c8 = (tid & 7) * 8;
    *(uint4*)&Ql[r * KPAD + c8] =
        *(const uint4*)&q[base + (size_t)(q0 + r) * DH + c8];
  }

  const int r_own = tid >> 4;           // 0..15
  const int c_own = tid & 15;           // 0..15
  float O0 = 0.f, O1 = 0.f, O2 = 0.f, O3 = 0.f;   // dims c_own*4..+3
  float m_r = -1e30f, l_r = 0.f;        // owner threads tid<16

  const int nkt = (q0 + TQ - 1) / TK + 1;   // key tiles covering 0..q0+15

  for (int t = 0; t < nkt; ++t) {
    __syncthreads();
    {                                   // stage K,V tile (64 x 64)
      const int kr = tid >> 2, c16 = (tid & 3) * 16;
      const size_t g = base + (size_t)(t * TK + kr) * DH + c16;
      *(uint4*)&Kl[kr * KPAD + c16]     = *(const uint4*)&k[g];
      *(uint4*)&Kl[kr * KPAD + c16 + 8] = *(const uint4*)&k[g + 8];
      *(uint4*)&Vl[kr * KPAD + c16]     = *(const uint4*)&v[g];
      *(uint4*)&Vl[kr * KPAD + c16 + 8] = *(const uint4*)&v[g + 8];
    }
    __syncthreads();

    const int qg = q0 + r_own;
#pragma unroll
    for (int cc = 0; cc < 4; ++cc) {
      const int c = c_own + cc * 16;
      const int kg = t * TK + c;
      float s;
      if (kg > qg) {
        s = -1e30f;
      } else {
        s = 0.f;
#pragma unroll
        for (int j8 = 0; j8 < 8; ++j8) {
          s16x8 qa = *(const s16x8*)&Ql[r_own * KPAD + j8 * 8];
          s16x8 ka = *(const s16x8*)&Kl[c * KPAD + j8 * 8];
#pragma unroll
          for (int j = 0; j < 8; ++j)
            s += bf2f((u16)qa[j]) * bf2f((u16)ka[j]);
        }
      }
      Sl[r_own * SST + c] = s;
    }
    __syncthreads();

    if (tid < TQ) {                     // online softmax, one owner per row
      float mt = -1e30f;
      for (int c = 0; c < TK; ++c) mt = fmaxf(mt, Sl[tid * SST + c]);
      const float mn = fmaxf(m_r, mt);
      const float alpha = __expf(m_r - mn);
      float rs = 0.f;
      for (int c = 0; c < TK; ++c) {
        const float p = __expf(Sl[tid * SST + c] - mn);
        Sl[tid * SST + c] = p;
        rs += p;
      }
      l_r = l_r * alpha + rs;
      m_r = mn;
      al[tid] = alpha;
      if (t == nkt - 1) ll[tid] = l_r;
    }
    __syncthreads();

    const float a = al[r_own];
    O0 *= a; O1 *= a; O2 *= a; O3 *= a;
    for (int c = 0; c < TK; ++c) {
      const float p = Sl[r_own * SST + c];
      const u16* vp = &Vl[c * KPAD + c_own * 4];
      O0 += p * bf2f(vp[0]); O1 += p * bf2f(vp[1]);
      O2 += p * bf2f(vp[2]); O3 += p * bf2f(vp[3]);
    }
  }

  __syncthreads();
  const float linv = 1.0f / ll[r_own];  // l >= 1 always
  const int b = bh / NH, h = bh % NH;
  const int qg = q0 + r_own;
  float* op = &o[((size_t)(b * S_LEN + qg)) * DM + h * DH + c_own * 4];
  op[0] = O0 * linv; op[1] = O1 * linv;
  op[2] = O2 * linv; op[3] = O3 * linv;
}

// ---------------------------------------------------------------------------
// Scalar in-place out-projection on d_out (FLOAT32): block stages its 64
// full rows into LDS FIRST as bf16 (96 KiB; all reads precede all writes;
// rows are block-private), then each thread computes dot(row, wo-row) and
// overwrites with the f32 result. wo f32, L2-resident.
// ---------------------------------------------------------------------------
__global__ __launch_bounds__(256) void out_proj_scalar(
    float* __restrict__ io, const float* __restrict__ wo)
{
  const int mT = blockIdx.x * 64;
  const int tid = threadIdx.x;

  __shared__ u16 Al[64 * DM];           // 96 KiB

  for (int i = tid; i < 64 * DM / 4; i += 256) {
    const int r = (i * 4) / DM, c = (i * 4) % DM;
    const float4 f4 = *(const float4*)&io[(size_t)(mT + r) * DM + c];
    Al[r * DM + c]     = f2bf(f4.x);
    Al[r * DM + c + 1] = f2bf(f4.y);
    Al[r * DM + c + 2] = f2bf(f4.z);
    Al[r * DM + c + 3] = f2bf(f4.w);
  }
  __syncthreads();

  const int r = tid >> 2;               // 0..63
  const int c0 = tid & 3;
  for (int cc = 0; cc < DM / 4; ++cc) {
    const int c = c0 + cc * 4;          // 0..767
    float acc = 0.f;
    for (int k = 0; k < DM; k += 4) {
      const float4 w4 = *(const float4*)&wo[(size_t)c * DM + k];
      acc += bf2f(Al[r * DM + k])     * w4.x
           + bf2f(Al[r * DM + k + 1]) * w4.y
           + bf2f(Al[r * DM + k + 2]) * w4.z
           + bf2f(Al[r * DM + k + 3]) * w4.w;
    }
    io[(size_t)(mT + r) * DM + c] = acc;
  }
}

// ---------------------------------------------------------------------------
extern "C" void kernel_launch(void* const* d_in, const int* in_sizes, int n_in,
                              void* d_out, int out_size, void* d_ws, size_t ws_size,
                              hipStream_t stream) {
  const float* x  = (const float*)d_in[0];   // inputs: float32 (confirmed r4)
  const float* wq = (const float*)d_in[1];
  const float* wk = (const float*)d_in[2];
  const float* wv = (const float*)d_in[3];
  const float* wo = (const float*)d_in[4];
  float* out = (float*)d_out;                // output: FLOAT32 (ref dtype)
  u16* ws  = (u16*)d_ws;

  const size_t QKV = (size_t)B_SZ * S_LEN * DM;  // 6291456 elems
  u16* qw = ws;                                  // ws: 3*QKV*2 = 37.7 MB
  u16* kw = ws + QKV;
  u16* vw = ws + 2 * QKV;

  qkv_gemm_scalar<<<dim3(8192 / 16, DM / 16, 3), 256, 0, stream>>>(
      x, wq, wk, wv, qw, kw, vw);
  rope_scalar<<<dim3(2 * NPAIRS / 256), 256, 0, stream>>>(qw, kw);
  attn_scalar_kernel<<<dim3(S_LEN / TQ, B_SZ * NH), 256, 0, stream>>>(
      qw, kw, vw, out);
  out_proj_scalar<<<dim3(8192 / 64), 256, 0, stream>>>(out, wo);
}

// Round 7
// 691.976 us; speedup vs baseline: 10.4322x; 10.4322x over previous
//
#include <hip/hip_runtime.h>
#include <hip/hip_bf16.h>

typedef float f32x4 __attribute__((ext_vector_type(4)));
typedef short s16x8 __attribute__((ext_vector_type(8)));
typedef unsigned short u16;

#define NH 12
#define DH 64
#define DM 768
#define S_LEN 2048
#define B_SZ 4

static __device__ __forceinline__ u16 f2bf(float f) {
  __hip_bfloat16 h = __float2bfloat16(f);
  return __builtin_bit_cast(u16, h);
}
// load 8 consecutive f32 from global, return packed bf16 x8
static __device__ __forceinline__ s16x8 ld8_f32_to_bf16(const float* p) {
  float4 a = *(const float4*)p;
  float4 b = *(const float4*)(p + 4);
  s16x8 r;
  r[0] = (short)f2bf(a.x); r[1] = (short)f2bf(a.y);
  r[2] = (short)f2bf(a.z); r[3] = (short)f2bf(a.w);
  r[4] = (short)f2bf(b.x); r[5] = (short)f2bf(b.y);
  r[6] = (short)f2bf(b.z); r[7] = (short)f2bf(b.w);
  return r;
}

// ---------------------------------------------------------------------------
// RoPE cos/sin table: tab[pos*32+i] = {cos,sin}(pos * 10000^(-2i/64)).
// Precise sincosf (angles reach 2047 rad; native v_sin invalid out there).
// ---------------------------------------------------------------------------
__global__ __launch_bounds__(256) void rope_table_kernel(float2* __restrict__ tab) {
  const int idx = blockIdx.x * 256 + threadIdx.x;   // 0..65535 exact
  const int sl = idx >> 5, i = idx & 31;
  const float inv_freq = exp2f((float)(2 * i) * (-13.287712379549449f / 64.0f));
  float s, c;
  sincosf((float)sl * inv_freq, &s, &c);
  tab[idx] = make_float2(c, s);
}

// ---------------------------------------------------------------------------
// QKV projection + RoPE (r4-validated). f32 inputs -> bf16 at LDS staging.
// 64x64 tile, BK=32, 4 waves, C = x @ W^T via mfma 16x16x32 bf16.
// C/D layout (m89): col = lane&15, row = (lane>>4)*4 + r; RoPE partner
// (col^1, same row) is in lane^1. q pre-scaled by 1/8.
// ---------------------------------------------------------------------------
#define AST 40

__global__ __launch_bounds__(256) void qkv_rope_kernel(
    const float* __restrict__ x, const float* __restrict__ wq,
    const float* __restrict__ wk, const float* __restrict__ wv,
    const float2* __restrict__ tab,
    u16* __restrict__ qo, u16* __restrict__ ko, u16* __restrict__ vo)
{
  const int z = blockIdx.z;                 // 0=q 1=k 2=v
  const float* Wp = (z == 0) ? wq : (z == 1) ? wk : wv;
  u16* Op = (z == 0) ? qo : (z == 1) ? ko : vo;
  const int mTile = blockIdx.x * 64;
  const int nTile = blockIdx.y * 64;
  const int tid = threadIdx.x;
  const int wave = tid >> 6, lane = tid & 63;
  const int lm = lane & 15, lq = lane >> 4;

  __shared__ u16 Al[64 * AST];
  __shared__ u16 Wl[64 * AST];

  f32x4 acc[4];
#pragma unroll
  for (int i = 0; i < 4; ++i) acc[i] = (f32x4){0.f, 0.f, 0.f, 0.f};

  const int srow = tid >> 2, scol = (tid & 3) * 8;   // 64 rows x 32 cols

  for (int k0 = 0; k0 < DM; k0 += 32) {
    __syncthreads();
    *(s16x8*)&Al[srow * AST + scol] =
        ld8_f32_to_bf16(&x[(size_t)(mTile + srow) * DM + k0 + scol]);
    *(s16x8*)&Wl[srow * AST + scol] =
        ld8_f32_to_bf16(&Wp[(size_t)(nTile + srow) * DM + k0 + scol]);
    __syncthreads();
    s16x8 af = *(const s16x8*)&Al[(wave * 16 + lm) * AST + lq * 8];
#pragma unroll
    for (int nt = 0; nt < 4; ++nt) {
      s16x8 bf = *(const s16x8*)&Wl[(nt * 16 + lm) * AST + lq * 8];
      acc[nt] = __builtin_amdgcn_mfma_f32_16x16x32_bf16(af, bf, acc[nt], 0, 0, 0);
    }
  }

#pragma unroll
  for (int nt = 0; nt < 4; ++nt) {
#pragma unroll
    for (int r = 0; r < 4; ++r) {
      float val = acc[nt][r];
      float partner = __shfl_xor(val, 1);
      const int mI = mTile + wave * 16 + lq * 4 + r;   // token 0..8191
      const int nI = nTile + nt * 16 + lm;             // feature 0..767
      float res;
      if (z < 2) {
        const int d = nI & 63;
        const int sl = mI & (S_LEN - 1);
        const float2 cs = tab[sl * 32 + (d >> 1)];
        res = val * cs.x + partner * ((d & 1) ? cs.y : -cs.y);
        if (z == 0) res *= 0.125f;                     // fold 1/sqrt(Dh)
      } else {
        res = val;
      }
      const int b = mI >> 11, sl2 = mI & (S_LEN - 1);
      const int h = nI >> 6, dd = nI & 63;
      Op[(((size_t)(b * NH + h)) * S_LEN + sl2) * DH + dd] = f2bf(res);
    }
  }
}

// ---------------------------------------------------------------------------
// MFMA flash attention (m120 pattern). Block = 4 waves = 64 queries of one
// (b,h); wave w owns queries w*16..+15. Per 64-key tile: K row-major
// [key][d], V transposed [d][key] (stride 72 bf16). QK^T and PV are
// 16x16x32 MFMAs; P goes C-layout -> per-wave LDS -> A-layout. Online
// softmax (m,l) in registers. Output FLOAT32 to d_out (b,s,dm).
// Semantics validated against the r6-passing scalar kernel.
// ---------------------------------------------------------------------------
#define KVST 72

__global__ __launch_bounds__(256) void attn_kernel(
    const u16* __restrict__ q, const u16* __restrict__ k,
    const u16* __restrict__ v, float* __restrict__ o)
{
  const int qt = (int)gridDim.x - 1 - (int)blockIdx.x;  // heavy tiles first
  const int bh = blockIdx.y;
  const size_t base = (size_t)bh * S_LEN * DH;
  const int tid = threadIdx.x;
  const int wave = tid >> 6, lane = tid & 63;
  const int lm = lane & 15, lq = lane >> 4;

  __shared__ u16 Kl[64 * KVST];
  __shared__ u16 Vt[64 * KVST];
  __shared__ u16 Pl[4 * 16 * KVST];

  const int qrow0 = qt * 64 + wave * 16;
  s16x8 aq[2];
#pragma unroll
  for (int kk = 0; kk < 2; ++kk)
    aq[kk] = *(const s16x8*)&q[base + (size_t)(qrow0 + lm) * DH + kk * 32 + lq * 8];

  f32x4 Oacc[4];
#pragma unroll
  for (int i = 0; i < 4; ++i) Oacc[i] = (f32x4){0.f, 0.f, 0.f, 0.f};
  float m_i[4], l_i[4];
#pragma unroll
  for (int r = 0; r < 4; ++r) { m_i[r] = -1e30f; l_i[r] = 0.f; }

  const int key_s = tid >> 2;        // staged key row 0..63
  const int db = (tid & 3) * 16;     // d-offset 0/16/32/48

  for (int t = 0; t <= qt; ++t) {
    __syncthreads();   // prev iteration's Kl/Vt/Pl reads done
    {
      const uint4* kg = (const uint4*)&k[base + (size_t)(t * 64 + key_s) * DH + db];
      uint4 a0 = kg[0], a1 = kg[1];
      *(uint4*)&Kl[key_s * KVST + db] = a0;
      *(uint4*)&Kl[key_s * KVST + db + 8] = a1;
      const uint4* vg = (const uint4*)&v[base + (size_t)(t * 64 + key_s) * DH + db];
      uint4 b0 = vg[0], b1 = vg[1];
      const u16* vp0 = (const u16*)&b0;
      const u16* vp1 = (const u16*)&b1;
#pragma unroll
      for (int ii = 0; ii < 8; ++ii) Vt[(db + ii) * KVST + key_s] = vp0[ii];
#pragma unroll
      for (int ii = 0; ii < 8; ++ii) Vt[(db + 8 + ii) * KVST + key_s] = vp1[ii];
    }
    __syncthreads();

    // S = Q K^T
    f32x4 S[4];
#pragma unroll
    for (int i = 0; i < 4; ++i) S[i] = (f32x4){0.f, 0.f, 0.f, 0.f};
#pragma unroll
    for (int kk = 0; kk < 2; ++kk) {
#pragma unroll
      for (int nt = 0; nt < 4; ++nt) {
        s16x8 kf = *(const s16x8*)&Kl[(nt * 16 + lm) * KVST + kk * 32 + lq * 8];
        S[nt] = __builtin_amdgcn_mfma_f32_16x16x32_bf16(aq[kk], kf, S[nt], 0, 0, 0);
      }
    }

    if (t == qt) {   // causal mask on diagonal tile (finite sentinel)
#pragma unroll
      for (int nt = 0; nt < 4; ++nt) {
#pragma unroll
        for (int r = 0; r < 4; ++r) {
          const int keyg = t * 64 + nt * 16 + lm;
          const int qg = qrow0 + lq * 4 + r;
          if (keyg > qg) S[nt][r] = -1e30f;
        }
      }
    }

    // online softmax; q-row lives in the 16 lanes sharing lq
#pragma unroll
    for (int r = 0; r < 4; ++r) {
      float rm = fmaxf(fmaxf(S[0][r], S[1][r]), fmaxf(S[2][r], S[3][r]));
      rm = fmaxf(rm, __shfl_xor(rm, 1));
      rm = fmaxf(rm, __shfl_xor(rm, 2));
      rm = fmaxf(rm, __shfl_xor(rm, 4));
      rm = fmaxf(rm, __shfl_xor(rm, 8));
      const float mn = fmaxf(m_i[r], rm);
      const float alpha = __expf(m_i[r] - mn);
      float rs = 0.f;
#pragma unroll
      for (int nt = 0; nt < 4; ++nt) {
        float p = __expf(S[nt][r] - mn);
        S[nt][r] = p;
        rs += p;
      }
      rs += __shfl_xor(rs, 1);
      rs += __shfl_xor(rs, 2);
      rs += __shfl_xor(rs, 4);
      rs += __shfl_xor(rs, 8);
      l_i[r] = l_i[r] * alpha + rs;
      m_i[r] = mn;
#pragma unroll
      for (int nt = 0; nt < 4; ++nt) Oacc[nt][r] *= alpha;
    }

    // P: C-layout regs -> per-wave LDS -> A-layout fragment (bf16)
#pragma unroll
    for (int nt = 0; nt < 4; ++nt)
#pragma unroll
      for (int r = 0; r < 4; ++r)
        Pl[wave * 16 * KVST + (lq * 4 + r) * KVST + nt * 16 + lm] = f2bf(S[nt][r]);
    __syncthreads();   // order P writes before cross-lane reads

    // O += P V
#pragma unroll
    for (int kk = 0; kk < 2; ++kk) {
      s16x8 pa = *(const s16x8*)&Pl[wave * 16 * KVST + lm * KVST + kk * 32 + lq * 8];
#pragma unroll
      for (int nt = 0; nt < 4; ++nt) {
        s16x8 vf = *(const s16x8*)&Vt[(nt * 16 + lm) * KVST + kk * 32 + lq * 8];
        Oacc[nt] = __builtin_amdgcn_mfma_f32_16x16x32_bf16(pa, vf, Oacc[nt], 0, 0, 0);
      }
    }
  }

  // normalize + store f32 to (b, s, h*64+d)
  const int b = bh / NH, h = bh % NH;
#pragma unroll
  for (int nt = 0; nt < 4; ++nt) {
#pragma unroll
    for (int r = 0; r < 4; ++r) {
      const int qg = qrow0 + lq * 4 + r;
      const int dd = nt * 16 + lm;
      o[((size_t)(b * S_LEN + qg)) * DM + h * DH + dd] = Oacc[nt][r] / l_i[r];
    }
  }
}

// ---------------------------------------------------------------------------
// In-place MFMA out-projection on d_out (f32), r4-validated. One block per
// 64-row tile: stage the block's 64x768 f32 rows into LDS as bf16 FIRST
// (rows are block-private => in-place safe), then C = A @ wo^T; B-fragments
// f32->bf16 direct from global (wo 2.25 MB, L2-resident). f32 stores.
// ---------------------------------------------------------------------------
#define OPST 776

__global__ __launch_bounds__(256) void out_proj_inplace_kernel(
    float* __restrict__ io, const float* __restrict__ wo)
{
  const int mT = blockIdx.x * 64;
  const int tid = threadIdx.x;
  const int wave = tid >> 6, lane = tid & 63;
  const int lm = lane & 15, lq = lane >> 4;

  __shared__ u16 Al[64 * OPST];         // 99.3 KB

#pragma unroll
  for (int i = 0; i < 24; ++i) {        // 64*768 = 256 thr * 24 * 8
    const int idx = (i * 256 + tid) * 8;
    const int r = idx / DM, c = idx % DM;
    *(s16x8*)&Al[r * OPST + c] = ld8_f32_to_bf16(&io[(size_t)(mT + r) * DM + c]);
  }
  __syncthreads();

  for (int nT = 0; nT < 12; ++nT) {
    f32x4 acc[4];
#pragma unroll
    for (int i = 0; i < 4; ++i) acc[i] = (f32x4){0.f, 0.f, 0.f, 0.f};
    for (int k0 = 0; k0 < DM; k0 += 32) {
      s16x8 af = *(const s16x8*)&Al[(wave * 16 + lm) * OPST + k0 + lq * 8];
#pragma unroll
      for (int nt = 0; nt < 4; ++nt) {
        s16x8 bf = ld8_f32_to_bf16(
            &wo[(size_t)(nT * 64 + nt * 16 + lm) * DM + k0 + lq * 8]);
        acc[nt] = __builtin_amdgcn_mfma_f32_16x16x32_bf16(af, bf, acc[nt], 0, 0, 0);
      }
    }
#pragma unroll
    for (int nt = 0; nt < 4; ++nt)
#pragma unroll
      for (int r = 0; r < 4; ++r)
        io[(size_t)(mT + wave * 16 + lq * 4 + r) * DM + nT * 64 + nt * 16 + lm] =
            acc[nt][r];
  }
}

// ---------------------------------------------------------------------------
extern "C" void kernel_launch(void* const* d_in, const int* in_sizes, int n_in,
                              void* d_out, int out_size, void* d_ws, size_t ws_size,
                              hipStream_t stream) {
  const float* x  = (const float*)d_in[0];   // inputs: float32 (r4-confirmed)
  const float* wq = (const float*)d_in[1];
  const float* wk = (const float*)d_in[2];
  const float* wv = (const float*)d_in[3];
  const float* wo = (const float*)d_in[4];
  float* out = (float*)d_out;                // output: float32 (r6-confirmed)
  u16* ws  = (u16*)d_ws;

  const size_t QKV = (size_t)B_SZ * S_LEN * DM;  // 6291456 elems
  u16* qw = ws;                                  // ws: 3*QKV*2 + 512KB = 38.3MB
  u16* kw = ws + QKV;
  u16* vw = ws + 2 * QKV;
  float2* tab = (float2*)(ws + 3 * QKV);         // 2048 x 32 cos/sin

  rope_table_kernel<<<dim3(S_LEN * 32 / 256), 256, 0, stream>>>(tab);
  qkv_rope_kernel<<<dim3(128, 12, 3), 256, 0, stream>>>(
      x, wq, wk, wv, tab, qw, kw, vw);
  attn_kernel<<<dim3(S_LEN / 64, B_SZ * NH), 256, 0, stream>>>(qw, kw, vw, out);
  out_proj_inplace_kernel<<<dim3(128), 256, 0, stream>>>(out, wo);
}

// Round 8
// 405.124 us; speedup vs baseline: 17.8188x; 1.7081x over previous
//
#include <hip/hip_runtime.h>
#include <hip/hip_bf16.h>

typedef float f32x4 __attribute__((ext_vector_type(4)));
typedef short s16x8 __attribute__((ext_vector_type(8)));
typedef unsigned short u16;

#define NH 12
#define DH 64
#define DM 768
#define S_LEN 2048
#define B_SZ 4

static __device__ __forceinline__ u16 f2bf(float f) {
  __hip_bfloat16 h = __float2bfloat16(f);
  return __builtin_bit_cast(u16, h);
}
// load 8 consecutive f32 from global, return packed bf16 x8
static __device__ __forceinline__ s16x8 ld8_f32_to_bf16(const float* p) {
  float4 a = *(const float4*)p;
  float4 b = *(const float4*)(p + 4);
  s16x8 r;
  r[0] = (short)f2bf(a.x); r[1] = (short)f2bf(a.y);
  r[2] = (short)f2bf(a.z); r[3] = (short)f2bf(a.w);
  r[4] = (short)f2bf(b.x); r[5] = (short)f2bf(b.y);
  r[6] = (short)f2bf(b.z); r[7] = (short)f2bf(b.w);
  return r;
}

// ---------------------------------------------------------------------------
// RoPE cos/sin table: tab[pos*32+i] = {cos,sin}(pos * 10000^(-2i/64)).
// Precise sincosf (angles reach 2047 rad; native v_sin invalid out there).
// ---------------------------------------------------------------------------
__global__ __launch_bounds__(256) void rope_table_kernel(float2* __restrict__ tab) {
  const int idx = blockIdx.x * 256 + threadIdx.x;   // 0..65535 exact
  const int sl = idx >> 5, i = idx & 31;
  const float inv_freq = exp2f((float)(2 * i) * (-13.287712379549449f / 64.0f));
  float s, c;
  sincosf((float)sl * inv_freq, &s, &c);
  tab[idx] = make_float2(c, s);
}

// ---------------------------------------------------------------------------
// QKV projection + RoPE (r7-validated). f32 inputs -> bf16 at LDS staging.
// 64x64 tile, BK=32, 4 waves, C = x @ W^T via mfma 16x16x32 bf16.
// ---------------------------------------------------------------------------
#define AST 40

__global__ __launch_bounds__(256) void qkv_rope_kernel(
    const float* __restrict__ x, const float* __restrict__ wq,
    const float* __restrict__ wk, const float* __restrict__ wv,
    const float2* __restrict__ tab,
    u16* __restrict__ qo, u16* __restrict__ ko, u16* __restrict__ vo)
{
  const int z = blockIdx.z;                 // 0=q 1=k 2=v
  const float* Wp = (z == 0) ? wq : (z == 1) ? wk : wv;
  u16* Op = (z == 0) ? qo : (z == 1) ? ko : vo;
  const int mTile = blockIdx.x * 64;
  const int nTile = blockIdx.y * 64;
  const int tid = threadIdx.x;
  const int wave = tid >> 6, lane = tid & 63;
  const int lm = lane & 15, lq = lane >> 4;

  __shared__ u16 Al[64 * AST];
  __shared__ u16 Wl[64 * AST];

  f32x4 acc[4];
#pragma unroll
  for (int i = 0; i < 4; ++i) acc[i] = (f32x4){0.f, 0.f, 0.f, 0.f};

  const int srow = tid >> 2, scol = (tid & 3) * 8;   // 64 rows x 32 cols

  for (int k0 = 0; k0 < DM; k0 += 32) {
    __syncthreads();
    *(s16x8*)&Al[srow * AST + scol] =
        ld8_f32_to_bf16(&x[(size_t)(mTile + srow) * DM + k0 + scol]);
    *(s16x8*)&Wl[srow * AST + scol] =
        ld8_f32_to_bf16(&Wp[(size_t)(nTile + srow) * DM + k0 + scol]);
    __syncthreads();
    s16x8 af = *(const s16x8*)&Al[(wave * 16 + lm) * AST + lq * 8];
#pragma unroll
    for (int nt = 0; nt < 4; ++nt) {
      s16x8 bf = *(const s16x8*)&Wl[(nt * 16 + lm) * AST + lq * 8];
      acc[nt] = __builtin_amdgcn_mfma_f32_16x16x32_bf16(af, bf, acc[nt], 0, 0, 0);
    }
  }

  // C/D layout (m89): col = lane&15, row = (lane>>4)*4 + r; RoPE partner in lane^1
#pragma unroll
  for (int nt = 0; nt < 4; ++nt) {
#pragma unroll
    for (int r = 0; r < 4; ++r) {
      float val = acc[nt][r];
      float partner = __shfl_xor(val, 1);
      const int mI = mTile + wave * 16 + lq * 4 + r;   // token 0..8191
      const int nI = nTile + nt * 16 + lm;             // feature 0..767
      float res;
      if (z < 2) {
        const int d = nI & 63;
        const int sl = mI & (S_LEN - 1);
        const float2 cs = tab[sl * 32 + (d >> 1)];
        res = val * cs.x + partner * ((d & 1) ? cs.y : -cs.y);
        if (z == 0) res *= 0.125f;                     // fold 1/sqrt(Dh)
      } else {
        res = val;
      }
      const int b = mI >> 11, sl2 = mI & (S_LEN - 1);
      const int h = nI >> 6, dd = nI & 63;
      Op[(((size_t)(b * NH + h)) * S_LEN + sl2) * DH + dd] = f2bf(res);
    }
  }
}

// ---------------------------------------------------------------------------
// MFMA flash attention (r7-validated). Block = 4 waves = 64 queries of one
// (b,h). Output now BF16 to aw (b,s,dm) — feeds the out-proj GEMM.
// ---------------------------------------------------------------------------
#define KVST 72

__global__ __launch_bounds__(256) void attn_kernel(
    const u16* __restrict__ q, const u16* __restrict__ k,
    const u16* __restrict__ v, u16* __restrict__ o)
{
  const int qt = (int)gridDim.x - 1 - (int)blockIdx.x;  // heavy tiles first
  const int bh = blockIdx.y;
  const size_t base = (size_t)bh * S_LEN * DH;
  const int tid = threadIdx.x;
  const int wave = tid >> 6, lane = tid & 63;
  const int lm = lane & 15, lq = lane >> 4;

  __shared__ u16 Kl[64 * KVST];
  __shared__ u16 Vt[64 * KVST];
  __shared__ u16 Pl[4 * 16 * KVST];

  const int qrow0 = qt * 64 + wave * 16;
  s16x8 aq[2];
#pragma unroll
  for (int kk = 0; kk < 2; ++kk)
    aq[kk] = *(const s16x8*)&q[base + (size_t)(qrow0 + lm) * DH + kk * 32 + lq * 8];

  f32x4 Oacc[4];
#pragma unroll
  for (int i = 0; i < 4; ++i) Oacc[i] = (f32x4){0.f, 0.f, 0.f, 0.f};
  float m_i[4], l_i[4];
#pragma unroll
  for (int r = 0; r < 4; ++r) { m_i[r] = -1e30f; l_i[r] = 0.f; }

  const int key_s = tid >> 2;        // staged key row 0..63
  const int db = (tid & 3) * 16;     // d-offset 0/16/32/48

  for (int t = 0; t <= qt; ++t) {
    __syncthreads();   // prev iteration's Kl/Vt/Pl reads done
    {
      const uint4* kg = (const uint4*)&k[base + (size_t)(t * 64 + key_s) * DH + db];
      uint4 a0 = kg[0], a1 = kg[1];
      *(uint4*)&Kl[key_s * KVST + db] = a0;
      *(uint4*)&Kl[key_s * KVST + db + 8] = a1;
      const uint4* vg = (const uint4*)&v[base + (size_t)(t * 64 + key_s) * DH + db];
      uint4 b0 = vg[0], b1 = vg[1];
      const u16* vp0 = (const u16*)&b0;
      const u16* vp1 = (const u16*)&b1;
#pragma unroll
      for (int ii = 0; ii < 8; ++ii) Vt[(db + ii) * KVST + key_s] = vp0[ii];
#pragma unroll
      for (int ii = 0; ii < 8; ++ii) Vt[(db + 8 + ii) * KVST + key_s] = vp1[ii];
    }
    __syncthreads();

    // S = Q K^T
    f32x4 S[4];
#pragma unroll
    for (int i = 0; i < 4; ++i) S[i] = (f32x4){0.f, 0.f, 0.f, 0.f};
#pragma unroll
    for (int kk = 0; kk < 2; ++kk) {
#pragma unroll
      for (int nt = 0; nt < 4; ++nt) {
        s16x8 kf = *(const s16x8*)&Kl[(nt * 16 + lm) * KVST + kk * 32 + lq * 8];
        S[nt] = __builtin_amdgcn_mfma_f32_16x16x32_bf16(aq[kk], kf, S[nt], 0, 0, 0);
      }
    }

    if (t == qt) {   // causal mask on diagonal tile (finite sentinel)
#pragma unroll
      for (int nt = 0; nt < 4; ++nt) {
#pragma unroll
        for (int r = 0; r < 4; ++r) {
          const int keyg = t * 64 + nt * 16 + lm;
          const int qg = qrow0 + lq * 4 + r;
          if (keyg > qg) S[nt][r] = -1e30f;
        }
      }
    }

    // online softmax; q-row lives in the 16 lanes sharing lq
#pragma unroll
    for (int r = 0; r < 4; ++r) {
      float rm = fmaxf(fmaxf(S[0][r], S[1][r]), fmaxf(S[2][r], S[3][r]));
      rm = fmaxf(rm, __shfl_xor(rm, 1));
      rm = fmaxf(rm, __shfl_xor(rm, 2));
      rm = fmaxf(rm, __shfl_xor(rm, 4));
      rm = fmaxf(rm, __shfl_xor(rm, 8));
      const float mn = fmaxf(m_i[r], rm);
      const float alpha = __expf(m_i[r] - mn);
      float rs = 0.f;
#pragma unroll
      for (int nt = 0; nt < 4; ++nt) {
        float p = __expf(S[nt][r] - mn);
        S[nt][r] = p;
        rs += p;
      }
      rs += __shfl_xor(rs, 1);
      rs += __shfl_xor(rs, 2);
      rs += __shfl_xor(rs, 4);
      rs += __shfl_xor(rs, 8);
      l_i[r] = l_i[r] * alpha + rs;
      m_i[r] = mn;
#pragma unroll
      for (int nt = 0; nt < 4; ++nt) Oacc[nt][r] *= alpha;
    }

    // P: C-layout regs -> per-wave LDS -> A-layout fragment (bf16)
#pragma unroll
    for (int nt = 0; nt < 4; ++nt)
#pragma unroll
      for (int r = 0; r < 4; ++r)
        Pl[wave * 16 * KVST + (lq * 4 + r) * KVST + nt * 16 + lm] = f2bf(S[nt][r]);
    __syncthreads();   // order P writes before cross-lane reads

    // O += P V
#pragma unroll
    for (int kk = 0; kk < 2; ++kk) {
      s16x8 pa = *(const s16x8*)&Pl[wave * 16 * KVST + lm * KVST + kk * 32 + lq * 8];
#pragma unroll
      for (int nt = 0; nt < 4; ++nt) {
        s16x8 vf = *(const s16x8*)&Vt[(nt * 16 + lm) * KVST + kk * 32 + lq * 8];
        Oacc[nt] = __builtin_amdgcn_mfma_f32_16x16x32_bf16(pa, vf, Oacc[nt], 0, 0, 0);
      }
    }
  }

  // normalize + store bf16 to aw (b, s, h*64+d)
  const int b = bh / NH, h = bh % NH;
#pragma unroll
  for (int nt = 0; nt < 4; ++nt) {
#pragma unroll
    for (int r = 0; r < 4; ++r) {
      const int qg = qrow0 + lq * 4 + r;
      const int dd = nt * 16 + lm;
      o[((size_t)(b * S_LEN + qg)) * DM + h * DH + dd] = f2bf(Oacc[nt][r] / l_i[r]);
    }
  }
}

// ---------------------------------------------------------------------------
// Out-projection GEMM (standard, not in-place): C = aw @ wo^T. A bf16 from
// ws, B f32->bf16 at staging, C f32 to d_out. 64x64 tile, BK=32, grid
// 128x12 = 1536 blocks (vs the 128-block 1-block/CU in-place version that
// ate 325 us at 1.2% MfmaUtil).
// ---------------------------------------------------------------------------
__global__ __launch_bounds__(256) void out_proj_kernel(
    const u16* __restrict__ a, const float* __restrict__ wo,
    float* __restrict__ c)
{
  const int mTile = blockIdx.x * 64;
  const int nTile = blockIdx.y * 64;
  const int tid = threadIdx.x;
  const int wave = tid >> 6, lane = tid & 63;
  const int lm = lane & 15, lq = lane >> 4;

  __shared__ u16 Al[64 * AST];
  __shared__ u16 Wl[64 * AST];

  f32x4 acc[4];
#pragma unroll
  for (int i = 0; i < 4; ++i) acc[i] = (f32x4){0.f, 0.f, 0.f, 0.f};

  const int srow = tid >> 2, scol = (tid & 3) * 8;

  for (int k0 = 0; k0 < DM; k0 += 32) {
    __syncthreads();
    *(uint4*)&Al[srow * AST + scol] =
        *(const uint4*)&a[(size_t)(mTile + srow) * DM + k0 + scol];
    *(s16x8*)&Wl[srow * AST + scol] =
        ld8_f32_to_bf16(&wo[(size_t)(nTile + srow) * DM + k0 + scol]);
    __syncthreads();
    s16x8 af = *(const s16x8*)&Al[(wave * 16 + lm) * AST + lq * 8];
#pragma unroll
    for (int nt = 0; nt < 4; ++nt) {
      s16x8 bf = *(const s16x8*)&Wl[(nt * 16 + lm) * AST + lq * 8];
      acc[nt] = __builtin_amdgcn_mfma_f32_16x16x32_bf16(af, bf, acc[nt], 0, 0, 0);
    }
  }

#pragma unroll
  for (int nt = 0; nt < 4; ++nt)
#pragma unroll
    for (int r = 0; r < 4; ++r)
      c[(size_t)(mTile + wave * 16 + lq * 4 + r) * DM + nTile + nt * 16 + lm] =
          acc[nt][r];
}

// ---------------------------------------------------------------------------
extern "C" void kernel_launch(void* const* d_in, const int* in_sizes, int n_in,
                              void* d_out, int out_size, void* d_ws, size_t ws_size,
                              hipStream_t stream) {
  const float* x  = (const float*)d_in[0];   // inputs: float32 (r4-confirmed)
  const float* wq = (const float*)d_in[1];
  const float* wk = (const float*)d_in[2];
  const float* wv = (const float*)d_in[3];
  const float* wo = (const float*)d_in[4];
  float* out = (float*)d_out;                // output: float32 (r6-confirmed)
  u16* ws  = (u16*)d_ws;

  const size_t QKV = (size_t)B_SZ * S_LEN * DM;  // 6291456 elems
  u16* qw = ws;                                  // ws: 4*QKV*2 + 512KB = 50.9MB
  u16* kw = ws + QKV;
  u16* vw = ws + 2 * QKV;
  u16* aw = ws + 3 * QKV;                        // attention out, bf16 (b,s,dm)
  float2* tab = (float2*)(ws + 4 * QKV);         // 2048 x 32 cos/sin

  rope_table_kernel<<<dim3(S_LEN * 32 / 256), 256, 0, stream>>>(tab);
  qkv_rope_kernel<<<dim3(128, 12, 3), 256, 0, stream>>>(
      x, wq, wk, wv, tab, qw, kw, vw);
  attn_kernel<<<dim3(S_LEN / 64, B_SZ * NH), 256, 0, stream>>>(qw, kw, vw, aw);
  out_proj_kernel<<<dim3(128, 12), 256, 0, stream>>>(aw, wo, out);
}

// Round 9
// 389.303 us; speedup vs baseline: 18.5429x; 1.0406x over previous
//
#include <hip/hip_runtime.h>
#include <hip/hip_bf16.h>

typedef float f32x4 __attribute__((ext_vector_type(4)));
typedef short s16x8 __attribute__((ext_vector_type(8)));
typedef unsigned short u16;

#define NH 12
#define DH 64
#define DM 768
#define S_LEN 2048
#define B_SZ 4

static __device__ __forceinline__ u16 f2bf(float f) {
  __hip_bfloat16 h = __float2bfloat16(f);
  return __builtin_bit_cast(u16, h);
}
// load 8 consecutive f32 from global, return packed bf16 x8
static __device__ __forceinline__ s16x8 ld8_f32_to_bf16(const float* p) {
  float4 a = *(const float4*)p;
  float4 b = *(const float4*)(p + 4);
  s16x8 r;
  r[0] = (short)f2bf(a.x); r[1] = (short)f2bf(a.y);
  r[2] = (short)f2bf(a.z); r[3] = (short)f2bf(a.w);
  r[4] = (short)f2bf(b.x); r[5] = (short)f2bf(b.y);
  r[6] = (short)f2bf(b.z); r[7] = (short)f2bf(b.w);
  return r;
}

// ---------------------------------------------------------------------------
// RoPE cos/sin table: tab[pos*32+i] = {cos,sin}(pos * 10000^(-2i/64)).
// Precise sincosf (angles reach 2047 rad; native v_sin invalid out there).
// ---------------------------------------------------------------------------
__global__ __launch_bounds__(256) void rope_table_kernel(float2* __restrict__ tab) {
  const int idx = blockIdx.x * 256 + threadIdx.x;   // 0..65535 exact
  const int sl = idx >> 5, i = idx & 31;
  const float inv_freq = exp2f((float)(2 * i) * (-13.287712379549449f / 64.0f));
  float s, c;
  sincosf((float)sl * inv_freq, &s, &c);
  tab[idx] = make_float2(c, s);
}

// ---------------------------------------------------------------------------
// QKV projection + RoPE (r7-validated GEMM core). f32 in -> bf16 staging.
// q: (b,h,s,d), pre-scaled by 0.125*log2(e)  [exp2-softmax units]
// k: (b,h,s,d)
// v: (b,h,d,s)  TRANSPOSED — epilogue stores are scalar anyway, so the
//               transpose is free here and removes the attn LDS transpose.
// ---------------------------------------------------------------------------
#define AST 40
#define QSCALE 0.18033688011112042f   // 0.125 * log2(e)

__global__ __launch_bounds__(256) void qkv_rope_kernel(
    const float* __restrict__ x, const float* __restrict__ wq,
    const float* __restrict__ wk, const float* __restrict__ wv,
    const float2* __restrict__ tab,
    u16* __restrict__ qo, u16* __restrict__ ko, u16* __restrict__ vo)
{
  const int z = blockIdx.z;                 // 0=q 1=k 2=v
  const float* Wp = (z == 0) ? wq : (z == 1) ? wk : wv;
  u16* Op = (z == 0) ? qo : (z == 1) ? ko : vo;
  const int mTile = blockIdx.x * 64;
  const int nTile = blockIdx.y * 64;
  const int tid = threadIdx.x;
  const int wave = tid >> 6, lane = tid & 63;
  const int lm = lane & 15, lq = lane >> 4;

  __shared__ u16 Al[64 * AST];
  __shared__ u16 Wl[64 * AST];

  f32x4 acc[4];
#pragma unroll
  for (int i = 0; i < 4; ++i) acc[i] = (f32x4){0.f, 0.f, 0.f, 0.f};

  const int srow = tid >> 2, scol = (tid & 3) * 8;   // 64 rows x 32 cols

  for (int k0 = 0; k0 < DM; k0 += 32) {
    __syncthreads();
    *(s16x8*)&Al[srow * AST + scol] =
        ld8_f32_to_bf16(&x[(size_t)(mTile + srow) * DM + k0 + scol]);
    *(s16x8*)&Wl[srow * AST + scol] =
        ld8_f32_to_bf16(&Wp[(size_t)(nTile + srow) * DM + k0 + scol]);
    __syncthreads();
    s16x8 af = *(const s16x8*)&Al[(wave * 16 + lm) * AST + lq * 8];
#pragma unroll
    for (int nt = 0; nt < 4; ++nt) {
      s16x8 bf = *(const s16x8*)&Wl[(nt * 16 + lm) * AST + lq * 8];
      acc[nt] = __builtin_amdgcn_mfma_f32_16x16x32_bf16(af, bf, acc[nt], 0, 0, 0);
    }
  }

  // C/D layout (m89): col = lane&15, row = (lane>>4)*4 + r; RoPE partner in lane^1
#pragma unroll
  for (int nt = 0; nt < 4; ++nt) {
#pragma unroll
    for (int r = 0; r < 4; ++r) {
      float val = acc[nt][r];
      float partner = __shfl_xor(val, 1);
      const int mI = mTile + wave * 16 + lq * 4 + r;   // token 0..8191
      const int nI = nTile + nt * 16 + lm;             // feature 0..767
      const int b = mI >> 11, sl2 = mI & (S_LEN - 1);
      const int h = nI >> 6, dd = nI & 63;
      float res;
      if (z < 2) {
        const float2 cs = tab[sl2 * 32 + (dd >> 1)];
        res = val * cs.x + partner * ((dd & 1) ? cs.y : -cs.y);
        if (z == 0) res *= QSCALE;
        Op[(((size_t)(b * NH + h)) * S_LEN + sl2) * DH + dd] = f2bf(res);
      } else {
        // v transposed: (b,h,d,s)
        Op[(((size_t)(b * NH + h)) * DH + dd) * S_LEN + sl2] = f2bf(val);
      }
    }
  }
}

// ---------------------------------------------------------------------------
// MFMA flash attention. Block = 4 waves, Q-tile = 128 queries of one (b,h):
// wave w owns m-groups {q0+w*16, q0+64+w*16} (16 rows each). Per 64-key
// tile: K staged [key][d], V^T staged [d][key] — both vectorized uint4
// copies (no scalar transpose; v arrives pre-transposed). QK^T and PV are
// 16x16x32 MFMAs; P goes C-layout -> PER-WAVE LDS -> A-layout (no block
// barrier needed: same-wave DS ops are ordered). Online softmax in exp2
// units (q pre-scaled by log2e/8). Fully-masked m-group tiles skipped
// (wave-uniform branch). Output bf16 to aw (b,s,dm).
// ---------------------------------------------------------------------------
#define KVST 72

__global__ __launch_bounds__(256) void attn_kernel(
    const u16* __restrict__ q, const u16* __restrict__ k,
    const u16* __restrict__ vt, u16* __restrict__ o)
{
  const int qt = (int)gridDim.x - 1 - (int)blockIdx.x;  // heavy tiles first
  const int bh = blockIdx.y;
  const size_t base = (size_t)bh * S_LEN * DH;          // same for (s,d)/(d,s)
  const int tid = threadIdx.x;
  const int wave = tid >> 6, lane = tid & 63;
  const int lm = lane & 15, lq = lane >> 4;

  __shared__ u16 Kl[64 * KVST];            // [key][d]
  __shared__ u16 Vl[64 * KVST];            // [d][key]
  __shared__ u16 Pl[4 * 32 * KVST];        // per-wave 32 q-rows x 64 keys

  const int q0 = qt * 128;
  const int qm[2] = {q0 + wave * 16, q0 + 64 + wave * 16};

  s16x8 aq[2][2];
#pragma unroll
  for (int g = 0; g < 2; ++g)
#pragma unroll
    for (int kk = 0; kk < 2; ++kk)
      aq[g][kk] = *(const s16x8*)
          &q[base + (size_t)(qm[g] + lm) * DH + kk * 32 + lq * 8];

  f32x4 Oacc[2][4];
  float m_i[2][4], l_i[2][4];
#pragma unroll
  for (int g = 0; g < 2; ++g)
#pragma unroll
    for (int i = 0; i < 4; ++i) {
      Oacc[g][i] = (f32x4){0.f, 0.f, 0.f, 0.f};
      m_i[g][i] = -1e30f; l_i[g][i] = 0.f;
    }

  const int srow = tid >> 2, scol16 = (tid & 3) * 16;
  const int ntiles = 2 * qt + 2;           // keys 0 .. q0+127

  for (int t = 0; t < ntiles; ++t) {
    __syncthreads();                       // prev tile's Kl/Vl reads done
    {
      const uint4* kg = (const uint4*)
          &k[base + (size_t)(t * 64 + srow) * DH + scol16];
      uint4 a0 = kg[0], a1 = kg[1];
      *(uint4*)&Kl[srow * KVST + scol16] = a0;
      *(uint4*)&Kl[srow * KVST + scol16 + 8] = a1;
      const uint4* vg = (const uint4*)
          &vt[base + (size_t)srow * S_LEN + t * 64 + scol16];
      uint4 b0 = vg[0], b1 = vg[1];
      *(uint4*)&Vl[srow * KVST + scol16] = b0;
      *(uint4*)&Vl[srow * KVST + scol16 + 8] = b1;
    }
    __syncthreads();

#pragma unroll
    for (int g = 0; g < 2; ++g) {
      if (t * 64 > qm[g] + 15) continue;   // fully masked (wave-uniform)

      // S = Q K^T
      f32x4 S[4];
#pragma unroll
      for (int i = 0; i < 4; ++i) S[i] = (f32x4){0.f, 0.f, 0.f, 0.f};
#pragma unroll
      for (int kk = 0; kk < 2; ++kk) {
#pragma unroll
        for (int nt = 0; nt < 4; ++nt) {
          s16x8 kf = *(const s16x8*)&Kl[(nt * 16 + lm) * KVST + kk * 32 + lq * 8];
          S[nt] = __builtin_amdgcn_mfma_f32_16x16x32_bf16(aq[g][kk], kf, S[nt], 0, 0, 0);
        }
      }

      if (t * 64 + 63 > qm[g]) {           // diagonal tile: causal mask
#pragma unroll
        for (int nt = 0; nt < 4; ++nt)
#pragma unroll
          for (int r = 0; r < 4; ++r) {
            const int keyg = t * 64 + nt * 16 + lm;
            const int qg = qm[g] + lq * 4 + r;
            if (keyg > qg) S[nt][r] = -1e30f;
          }
      }

      // online softmax (exp2 units); row = 16 lanes sharing lq
#pragma unroll
      for (int r = 0; r < 4; ++r) {
        float rm = fmaxf(fmaxf(S[0][r], S[1][r]), fmaxf(S[2][r], S[3][r]));
        rm = fmaxf(rm, __shfl_xor(rm, 1));
        rm = fmaxf(rm, __shfl_xor(rm, 2));
        rm = fmaxf(rm, __shfl_xor(rm, 4));
        rm = fmaxf(rm, __shfl_xor(rm, 8));
        const float mn = fmaxf(m_i[g][r], rm);
        const float alpha = exp2f(m_i[g][r] - mn);
        float rs = 0.f;
#pragma unroll
        for (int nt = 0; nt < 4; ++nt) {
          float p = exp2f(S[nt][r] - mn);
          S[nt][r] = p;
          rs += p;
        }
        rs += __shfl_xor(rs, 1);
        rs += __shfl_xor(rs, 2);
        rs += __shfl_xor(rs, 4);
        rs += __shfl_xor(rs, 8);
        l_i[g][r] = l_i[g][r] * alpha + rs;
        m_i[g][r] = mn;
#pragma unroll
        for (int nt = 0; nt < 4; ++nt) Oacc[g][nt][r] *= alpha;
      }

      // P: C-layout regs -> per-wave LDS -> A-layout (same-wave: no barrier)
#pragma unroll
      for (int nt = 0; nt < 4; ++nt)
#pragma unroll
        for (int r = 0; r < 4; ++r)
          Pl[(wave * 32 + g * 16 + lq * 4 + r) * KVST + nt * 16 + lm] =
              f2bf(S[nt][r]);

      // O += P V
#pragma unroll
      for (int kk = 0; kk < 2; ++kk) {
        s16x8 pa = *(const s16x8*)
            &Pl[(wave * 32 + g * 16 + lm) * KVST + kk * 32 + lq * 8];
#pragma unroll
        for (int nt = 0; nt < 4; ++nt) {
          s16x8 vf = *(const s16x8*)&Vl[(nt * 16 + lm) * KVST + kk * 32 + lq * 8];
          Oacc[g][nt] = __builtin_amdgcn_mfma_f32_16x16x32_bf16(pa, vf, Oacc[g][nt], 0, 0, 0);
        }
      }
    }
  }

  // normalize + store bf16 to aw (b, s, h*64+d)
  const int b = bh / NH, h = bh % NH;
#pragma unroll
  for (int g = 0; g < 2; ++g)
#pragma unroll
    for (int nt = 0; nt < 4; ++nt)
#pragma unroll
      for (int r = 0; r < 4; ++r) {
        const int qg = qm[g] + lq * 4 + r;
        const int dd = nt * 16 + lm;
        o[((size_t)(b * S_LEN + qg)) * DM + h * DH + dd] =
            f2bf(Oacc[g][nt][r] / l_i[g][r]);
      }
}

// ---------------------------------------------------------------------------
// Out-projection GEMM (r8-validated): C = aw @ wo^T. A bf16, B f32->bf16 at
// staging, C f32 to d_out. 64x64 tile, BK=32, 1536 blocks.
// ---------------------------------------------------------------------------
__global__ __launch_bounds__(256) void out_proj_kernel(
    const u16* __restrict__ a, const float* __restrict__ wo,
    float* __restrict__ c)
{
  const int mTile = blockIdx.x * 64;
  const int nTile = blockIdx.y * 64;
  const int tid = threadIdx.x;
  const int wave = tid >> 6, lane = tid & 63;
  const int lm = lane & 15, lq = lane >> 4;

  __shared__ u16 Al[64 * AST];
  __shared__ u16 Wl[64 * AST];

  f32x4 acc[4];
#pragma unroll
  for (int i = 0; i < 4; ++i) acc[i] = (f32x4){0.f, 0.f, 0.f, 0.f};

  const int srow = tid >> 2, scol = (tid & 3) * 8;

  for (int k0 = 0; k0 < DM; k0 += 32) {
    __syncthreads();
    *(uint4*)&Al[srow * AST + scol] =
        *(const uint4*)&a[(size_t)(mTile + srow) * DM + k0 + scol];
    *(s16x8*)&Wl[srow * AST + scol] =
        ld8_f32_to_bf16(&wo[(size_t)(nTile + srow) * DM + k0 + scol]);
    __syncthreads();
    s16x8 af = *(const s16x8*)&Al[(wave * 16 + lm) * AST + lq * 8];
#pragma unroll
    for (int nt = 0; nt < 4; ++nt) {
      s16x8 bf = *(const s16x8*)&Wl[(nt * 16 + lm) * AST + lq * 8];
      acc[nt] = __builtin_amdgcn_mfma_f32_16x16x32_bf16(af, bf, acc[nt], 0, 0, 0);
    }
  }

#pragma unroll
  for (int nt = 0; nt < 4; ++nt)
#pragma unroll
    for (int r = 0; r < 4; ++r)
      c[(size_t)(mTile + wave * 16 + lq * 4 + r) * DM + nTile + nt * 16 + lm] =
          acc[nt][r];
}

// ---------------------------------------------------------------------------
extern "C" void kernel_launch(void* const* d_in, const int* in_sizes, int n_in,
                              void* d_out, int out_size, void* d_ws, size_t ws_size,
                              hipStream_t stream) {
  const float* x  = (const float*)d_in[0];   // inputs: float32 (r4-confirmed)
  const float* wq = (const float*)d_in[1];
  const float* wk = (const float*)d_in[2];
  const float* wv = (const float*)d_in[3];
  const float* wo = (const float*)d_in[4];
  float* out = (float*)d_out;                // output: float32 (r6-confirmed)
  u16* ws  = (u16*)d_ws;

  const size_t QKV = (size_t)B_SZ * S_LEN * DM;  // 6291456 elems
  u16* qw = ws;                                  // ws: 4*QKV*2 + 512KB = 50.9MB
  u16* kw = ws + QKV;
  u16* vw = ws + 2 * QKV;                        // v TRANSPOSED (b,h,d,s)
  u16* aw = ws + 3 * QKV;                        // attention out, bf16 (b,s,dm)
  float2* tab = (float2*)(ws + 4 * QKV);         // 2048 x 32 cos/sin

  rope_table_kernel<<<dim3(S_LEN * 32 / 256), 256, 0, stream>>>(tab);
  qkv_rope_kernel<<<dim3(128, 12, 3), 256, 0, stream>>>(
      x, wq, wk, wv, tab, qw, kw, vw);
  attn_kernel<<<dim3(S_LEN / 128, B_SZ * NH), 256, 0, stream>>>(qw, kw, vw, aw);
  out_proj_kernel<<<dim3(128, 12), 256, 0, stream>>>(aw, wo, out);
}